// Round 1
// baseline (476.936 us; speedup 1.0000x reference)
//
#include <hip/hip_runtime.h>
#include <math.h>

#define VOCAB 500
#define EMB   64
#define HID   64
#define BB    512
#define TT    512

// tanh(x) = sign(x) * (1 - 2e/(1+e)), e = exp(-2|x|)  (stable, ~1e-6 abs err)
__device__ __forceinline__ float fast_tanh(float x) {
    float ax = fabsf(x);
    float e  = __expf(-2.0f * ax);
    float r  = __builtin_amdgcn_rcpf(1.0f + e);
    float t  = fmaf(-2.0f * e, r, 1.0f);
    return copysignf(t, x);
}

// proj[v][j] = b_ih0[j] + sum_k W_ih0[j][k] * emb[v][k]
__global__ __launch_bounds__(64) void proj_kernel(
        const float* __restrict__ emb,
        const float* __restrict__ W_ih0,
        const float* __restrict__ b_ih0,
        float* __restrict__ proj) {
    const int v = blockIdx.x;
    const int j = threadIdx.x;
    const float4* e4 = (const float4*)(emb + v * EMB);
    const float4* w4 = (const float4*)(W_ih0 + j * EMB);
    float acc = b_ih0[j];
    #pragma unroll
    for (int k = 0; k < EMB / 4; ++k) {
        float4 e = e4[k];
        float4 w = w4[k];
        acc = fmaf(w.x, e.x, acc);
        acc = fmaf(w.y, e.y, acc);
        acc = fmaf(w.z, e.z, acc);
        acc = fmaf(w.w, e.w, acc);
    }
    proj[v * HID + j] = acc;
}

// One wave (64 lanes) per batch row; lane j owns hidden unit j.
// Recurrent weights resident in VGPRs; h-state broadcast via LDS.
__global__ __launch_bounds__(64) void rnn_kernel(
        const int*   __restrict__ x,
        const float* __restrict__ proj,
        const float* __restrict__ W_hh0,
        const float* __restrict__ b_hh0,
        const float* __restrict__ W_ih1,
        const float* __restrict__ W_hh1,
        const float* __restrict__ b_ih1,
        const float* __restrict__ b_hh1,
        const float* __restrict__ fc_w,
        const float* __restrict__ fc_b,
        float* __restrict__ out) {
    const int b = blockIdx.x;
    const int j = threadIdx.x;

    __shared__ __align__(16) float h1s[HID];
    __shared__ __align__(16) float h2s[HID];
    __shared__ int xls[TT];

    // stage this row's token indices into LDS
    for (int t = j; t < TT; t += 64) xls[t] = x[b * TT + t];

    // weight rows -> registers (static indices, fully unrolled => VGPRs)
    float whh0[HID], wih1[HID], whh1[HID];
    {
        const float4* a = (const float4*)(W_hh0 + j * HID);
        const float4* c = (const float4*)(W_ih1 + j * HID);
        const float4* d = (const float4*)(W_hh1 + j * HID);
        #pragma unroll
        for (int k = 0; k < HID / 4; ++k) {
            float4 t0 = a[k];
            whh0[4*k+0] = t0.x; whh0[4*k+1] = t0.y; whh0[4*k+2] = t0.z; whh0[4*k+3] = t0.w;
            float4 t1 = c[k];
            wih1[4*k+0] = t1.x; wih1[4*k+1] = t1.y; wih1[4*k+2] = t1.z; wih1[4*k+3] = t1.w;
            float4 t2 = d[k];
            whh1[4*k+0] = t2.x; whh1[4*k+1] = t2.y; whh1[4*k+2] = t2.z; whh1[4*k+3] = t2.w;
        }
    }
    const float bh0 = b_hh0[j];
    const float bi1 = b_ih1[j] + b_hh1[j];
    const float fcw = fc_w[j];

    h1s[j] = 0.0f;
    h2s[j] = 0.0f;
    __syncthreads();

    const float4* h1v = (const float4*)h1s;
    const float4* h2v = (const float4*)h2s;

    int   idx = xls[0];
    float xin = proj[idx * HID + j];   // prefetched input projection for t=0
    float h2n = 0.0f;

    for (int t = 0; t < TT; ++t) {
        // prefetch next step's projected input (hidden under this step's compute)
        const int   idxn = xls[(t + 1) & (TT - 1)];
        const float xinn = proj[idxn * HID + j];

        float acc1 = xin + bh0;
        float acc2 = bi1;
        #pragma unroll
        for (int k = 0; k < HID / 4; ++k) {
            float4 h = h1v[k];   // old h1 (uniform address -> broadcast)
            acc1 = fmaf(whh0[4*k+0], h.x, acc1);
            acc1 = fmaf(whh0[4*k+1], h.y, acc1);
            acc1 = fmaf(whh0[4*k+2], h.z, acc1);
            acc1 = fmaf(whh0[4*k+3], h.w, acc1);
            float4 g = h2v[k];   // old h2
            acc2 = fmaf(whh1[4*k+0], g.x, acc2);
            acc2 = fmaf(whh1[4*k+1], g.y, acc2);
            acc2 = fmaf(whh1[4*k+2], g.z, acc2);
            acc2 = fmaf(whh1[4*k+3], g.w, acc2);
        }
        const float h1n = fast_tanh(acc1);

        __syncthreads();          // (A) all lanes done reading old h1s/h2s
        h1s[j] = h1n;
        __syncthreads();          // (B) new h1 visible

        #pragma unroll
        for (int k = 0; k < HID / 4; ++k) {
            float4 h = h1v[k];    // new h1
            acc2 = fmaf(wih1[4*k+0], h.x, acc2);
            acc2 = fmaf(wih1[4*k+1], h.y, acc2);
            acc2 = fmaf(wih1[4*k+2], h.z, acc2);
            acc2 = fmaf(wih1[4*k+3], h.w, acc2);
        }
        h2n = fast_tanh(acc2);
        h2s[j] = h2n;             // old h2s reads all finished before (A)
        __syncthreads();          // (C) new h2 visible for next iteration

        xin = xinn;
    }

    // out[b] = fc_b + sum_j h2[j] * fc_w[j]
    float val = h2n * fcw;
    #pragma unroll
    for (int o = 32; o > 0; o >>= 1) val += __shfl_down(val, o, 64);
    if (j == 0) out[b] = val + fc_b[0];
}

extern "C" void kernel_launch(void* const* d_in, const int* in_sizes, int n_in,
                              void* d_out, int out_size, void* d_ws, size_t ws_size,
                              hipStream_t stream) {
    const int*   x     = (const int*)  d_in[0];
    const float* emb   = (const float*)d_in[1];
    const float* W_ih0 = (const float*)d_in[2];
    const float* W_hh0 = (const float*)d_in[3];
    const float* b_ih0 = (const float*)d_in[4];
    const float* b_hh0 = (const float*)d_in[5];
    const float* W_ih1 = (const float*)d_in[6];
    const float* W_hh1 = (const float*)d_in[7];
    const float* b_ih1 = (const float*)d_in[8];
    const float* b_hh1 = (const float*)d_in[9];
    const float* fc_w  = (const float*)d_in[10];
    const float* fc_b  = (const float*)d_in[11];
    float* out  = (float*)d_out;
    float* proj = (float*)d_ws;   // 500*64*4 = 128 KB scratch

    proj_kernel<<<VOCAB, 64, 0, stream>>>(emb, W_ih0, b_ih0, proj);
    rnn_kernel<<<BB, 64, 0, stream>>>(x, proj, W_hh0, b_hh0,
                                      W_ih1, W_hh1, b_ih1, b_hh1,
                                      fc_w, fc_b, out);
}